// Round 3
// baseline (737.813 us; speedup 1.0000x reference)
//
#include <hip/hip_runtime.h>
#include <hip/hip_bf16.h>
#include <stdint.h>

typedef __hip_bfloat16 bf16;
typedef __attribute__((ext_vector_type(8))) short short8;
typedef __attribute__((ext_vector_type(4))) float float4_t;

__device__ __forceinline__ short f2b_bits(float f) {
  union { float f; unsigned u; } v; v.f = f;
  unsigned r = (v.u + 0x7FFF + ((v.u >> 16) & 1)) >> 16;  // RNE
  return (short)r;
}
__device__ __forceinline__ bf16 f2b(float f) {
  short s = f2b_bits(f);
  bf16 h; __builtin_memcpy(&h, &s, 2);
  return h;
}
// load element idx from p (fp32 if f32 else bf16) -> bf16
__device__ __forceinline__ bf16 ld_bf16(const void* p, size_t idx, int f32) {
  if (f32) return f2b(((const float*)p)[idx]);
  return ((const bf16*)p)[idx];
}

// async global->LDS, 16B per lane. LDS dest must be wave-uniform base + lane*16.
__device__ __forceinline__ void gload_lds16(const void* g, void* l) {
  __builtin_amdgcn_global_load_lds(
      (const __attribute__((address_space(1))) void*)g,
      (__attribute__((address_space(3))) void*)l, 16, 0, 0);
}

// ---------- dtype detector: probe = bi (1024 elements) ----------
__global__ void detect_dtype(const void* probe, int* flag) {
  int lane = threadIdx.x;  // 64 threads
  const unsigned short* u = (const unsigned short*)probe;
  const float* fp = (const float*)probe;
  int cb = 0, cf = 0;
  for (int j = lane; j < 256; j += 64) {
    unsigned short he = u[2 * j];
    int e = (he >> 7) & 0xFF;
    cb += (e >= 0x60 && e <= 0x7E);
    float af = fabsf(fp[j]);
    cf += (af > 1e-9f && af < 1.0f);
  }
#pragma unroll
  for (int off = 32; off > 0; off >>= 1) {
    cb += __shfl_down(cb, off);
    cf += __shfl_down(cf, off);
  }
  if (lane == 0) *flag = (cf > cb) ? 1 : 0;  // 1 = inputs are fp32
}

// ---------- bulk convert x -> bf16 (copy if already bf16) ----------
__global__ __launch_bounds__(256) void cvt_x(const void* __restrict__ x,
                                             bf16* __restrict__ xb,
                                             const int* __restrict__ flagp,
                                             size_t n /* elements, mult of 8 */) {
  const int f32 = *flagp;
  size_t i = ((size_t)blockIdx.x * 256 + threadIdx.x) * 8;
  size_t stride = (size_t)gridDim.x * 256 * 8;
  for (; i < n; i += stride) {
    if (f32) {
      const float* xp = (const float*)x + i;
      float4_t f0 = *(const float4_t*)xp;
      float4_t f1 = *(const float4_t*)(xp + 4);
      short8 v;
      v[0] = f2b_bits(f0[0]); v[1] = f2b_bits(f0[1]);
      v[2] = f2b_bits(f0[2]); v[3] = f2b_bits(f0[3]);
      v[4] = f2b_bits(f1[0]); v[5] = f2b_bits(f1[1]);
      v[6] = f2b_bits(f1[2]); v[7] = f2b_bits(f1[3]);
      *(short8*)(xb + i) = v;
    } else {
      *(short8*)(xb + i) = *(const short8*)((const bf16*)x + i);
    }
  }
}

// ---------- transpose: dst[n*K+k] = src[k*N+n]; K,N multiples of 64 ----------
__global__ __launch_bounds__(256) void transpose_k(const void* __restrict__ src,
                                                   bf16* __restrict__ dst,
                                                   const int* __restrict__ flagp,
                                                   int K, int N) {
  const int f32 = *flagp;
  __shared__ bf16 tile[64][65];
  int kb = blockIdx.x * 64, nb = blockIdx.y * 64;
  int tx = threadIdx.x & 63;
  int ty = threadIdx.x >> 6;  // 0..3
#pragma unroll
  for (int i = 0; i < 64; i += 4)
    tile[ty + i][tx] = ld_bf16(src, (size_t)(kb + ty + i) * N + nb + tx, f32);
  __syncthreads();
#pragma unroll
  for (int i = 0; i < 64; i += 4)
    dst[(size_t)(nb + ty + i) * K + kb + tx] = tile[tx][ty + i];
}

// ---------- convert small arrays to canonical bf16 ----------
__global__ void cvt_misc(const void* bi, const void* bb, const void* bf_,
                         const void* bw, const void* bo, const void* Ww,
                         bf16* biC, bf16* bbfC, bf16* bwC, bf16* boC, bf16* WwC,
                         const int* flagp) {
  const int f32 = *flagp;
  int i = blockIdx.x * 256 + threadIdx.x;
  if (i < 1024) biC[i] = ld_bf16(bi, i, f32);
  if (i < 512)  bbfC[i] = ld_bf16(bb, i, f32);
  if (i < 512)  bbfC[512 + i] = ld_bf16(bf_, i, f32);
  if (i < 8)    bwC[i] = ld_bf16(bw, i, f32);
  if (i < 4096) boC[i] = ld_bf16(bo, i, f32);
  if (i < 8192) WwC[i] = ld_bf16(Ww, i, f32);
}

// ---------- MFMA GEMM: C = A(MxK) * BT(NxK)^T + bias [+resid] ----------------
// BM x BN tile, BK=64, 4 waves (2x2). 2-phase double-buffered K-loop
// (catalog T3-minimum recipe): issue tile t+1's global_load_lds BEFORE
// computing tile t; ONE barrier per K-step. The round-2 counters showed the
// old stage->sync->compute structure left every pipe idle (MfmaUtil 16.5%,
// VALUBusy 20%, HBM 10%): the barrier sat immediately after the load issue,
// eating full load latency per K-step. Now compute time hides most of it.
// Staging via global_load_lds (16B/lane) for bf16 operands; reg-staged
// convert fallback for fp32 A. LDS layout linear in V (=V*16B).
template <int BM, int BN>
__global__ __launch_bounds__(256) void gemm_bt(
    const void* __restrict__ A,      // M x K (bf16, or fp32 if *aF32)
    const bf16* __restrict__ BT,     // N x K
    const bf16* __restrict__ bias,   // N
    const void* __restrict__ resid,  // M x N (nullable; dtype follows rF32)
    void* __restrict__ C,            // M x N (bf16, or fp32 if *cF32)
    const int* __restrict__ aF32, const int* __restrict__ rF32,
    const int* __restrict__ cF32,
    int M, int N, int K, int clip_cols)
{
  constexpr int FM = BM / 32;  // 16-row fragments per wave (M)
  constexpr int FN = BN / 32;  // 16-col fragments per wave (N)
  __shared__ alignas(16) bf16 As[2][BM * 64];
  __shared__ alignas(16) bf16 Bs[2][BN * 64];
  const int af32 = aF32 ? *aF32 : 0;
  const int rf32 = rF32 ? *rF32 : 0;
  const int cf32 = cF32 ? *cF32 : 0;
  const int tid  = threadIdx.x;
  const int wave = tid >> 6;
  const int lane = tid & 63;
  const int m0 = blockIdx.x * BM;
  const int n0 = blockIdx.y * BN;
  const int wm = (wave >> 1) * (BM / 2);
  const int wn = (wave & 1) * (BN / 2);
  const int lm = lane & 15;
  const int lk = (lane >> 4) * 8;

  auto stage = [&](int buf, int k0) {
    // B tile: BN rows x 64 cols, async direct-to-LDS (always bf16)
#pragma unroll
    for (int i = 0; i < BN / 32; i++) {
      int V = tid + 256 * i;
      int row = V >> 3;
      int kc  = (V & 7) * 8;
      gload_lds16(BT + (size_t)(n0 + row) * K + k0 + kc, Bs[buf] + (size_t)V * 8);
    }
    // A tile: BM rows x 64 cols
#pragma unroll
    for (int i = 0; i < BM / 32; i++) {
      int V = tid + 256 * i;
      int row = V >> 3;
      int kc  = (V & 7) * 8;
      if (af32) {
        const float* ap = (const float*)A + (size_t)(m0 + row) * K + k0 + kc;
        float4_t f0 = *(const float4_t*)ap;
        float4_t f1 = *(const float4_t*)(ap + 4);
        short8 v;
        v[0] = f2b_bits(f0[0]); v[1] = f2b_bits(f0[1]);
        v[2] = f2b_bits(f0[2]); v[3] = f2b_bits(f0[3]);
        v[4] = f2b_bits(f1[0]); v[5] = f2b_bits(f1[1]);
        v[6] = f2b_bits(f1[2]); v[7] = f2b_bits(f1[3]);
        *(short8*)(As[buf] + (size_t)V * 8) = v;
      } else {
        gload_lds16((const bf16*)A + (size_t)(m0 + row) * K + k0 + kc,
                    As[buf] + (size_t)V * 8);
      }
    }
  };

  float4_t acc[FM][FN];
#pragma unroll
  for (int i = 0; i < FM; i++)
#pragma unroll
    for (int j = 0; j < FN; j++) acc[i][j] = (float4_t){0.f, 0.f, 0.f, 0.f};

  const int NT = K >> 6;  // K-tiles (K is a multiple of 64: 4096/1024/128)
  stage(0, 0);
  __syncthreads();  // drains vmcnt(0): buf0 ready

  for (int t = 0; t < NT; t++) {
    int cur = t & 1;
    if (t + 1 < NT) stage(cur ^ 1, (t + 1) << 6);  // prefetch next tile
#pragma unroll
    for (int kk = 0; kk < 64; kk += 32) {
      short8 af[FM], bfr[FN];
#pragma unroll
      for (int mi = 0; mi < FM; mi++)
        af[mi] = *(const short8*)(As[cur] + (wm + mi * 16 + lm) * 64 + kk + lk);
#pragma unroll
      for (int ni = 0; ni < FN; ni++)
        bfr[ni] = *(const short8*)(Bs[cur] + (wn + ni * 16 + lm) * 64 + kk + lk);
#pragma unroll
      for (int mi = 0; mi < FM; mi++)
#pragma unroll
        for (int ni = 0; ni < FN; ni++)
          acc[mi][ni] = __builtin_amdgcn_mfma_f32_16x16x32_bf16(
              af[mi], bfr[ni], acc[mi][ni], 0, 0, 0);
    }
    // one barrier per K-step: drains vmcnt(0) (next buf staged) and orders
    // this iteration's LDS reads before next iteration's overwrite of buf cur^1
    __syncthreads();
  }

  // epilogue: C/D layout col=lane&15, row=(lane>>4)*4+r
#pragma unroll
  for (int mi = 0; mi < FM; mi++) {
#pragma unroll
    for (int ni = 0; ni < FN; ni++) {
      int col = n0 + wn + ni * 16 + lm;
      float bv = __bfloat162float(bias[col]);
#pragma unroll
      for (int r = 0; r < 4; r++) {
        int row = m0 + wm + mi * 16 + (lane >> 4) * 4 + r;
        float v = acc[mi][ni][r] + bv;
        if (col < clip_cols) v = fminf(fmaxf(v, -10.f), 10.f);
        size_t idx = (size_t)row * N + col;
        if (resid) {
          v += rf32 ? ((const float*)resid)[idx]
                    : __bfloat162float(((const bf16*)resid)[idx]);
        }
        if (cf32) ((float*)C)[idx] = v;
        else      ((bf16*)C)[idx] = __float2bfloat16(v);
      }
    }
  }
}

// ---------- w_logits + softmax: one block per token ----------
__global__ __launch_bounds__(256) void wlogits_softmax(
    const bf16* __restrict__ h,   // 8192 x 1024
    const bf16* __restrict__ Ww,  // 1024 x 8
    const bf16* __restrict__ bw,  // 8
    float* __restrict__ wts)      // 8192 x 8
{
  int t = blockIdx.x;
  int tid = threadIdx.x;
  int p = tid >> 5;
  int l32 = tid & 31;
  const bf16* hr = h + (size_t)t * 1024;
  float s = 0.f;
  for (int k = l32; k < 1024; k += 32)
    s += __bfloat162float(hr[k]) * __bfloat162float(Ww[(size_t)k * 8 + p]);
#pragma unroll
  for (int off = 16; off > 0; off >>= 1) s += __shfl_down(s, off, 32);
  __shared__ float logits[8];
  if (l32 == 0) logits[p] = s + __bfloat162float(bw[p]);
  __syncthreads();
  if (tid == 0) {
    float mx = logits[0];
#pragma unroll
    for (int i = 1; i < 8; i++) mx = fmaxf(mx, logits[i]);
    float e[8]; float den = 0.f;
#pragma unroll
    for (int i = 0; i < 8; i++) { e[i] = expf(logits[i] - mx); den += e[i]; }
    float inv = 1.f / den;
#pragma unroll
    for (int i = 0; i < 8; i++) wts[(size_t)t * 8 + i] = e[i] * inv;
  }
}

// ---------- per-token combine: temporal mix + weighted aggregation ----------
__global__ __launch_bounds__(128) void build_combined(
    const bf16* __restrict__ bcfs,  // 8192 x 1024: cols 0..511 bc(p,d), 512..1023 fs(p,k)
    const float* __restrict__ wts,  // 8192 x 8
    bf16* __restrict__ comb)        // 8192 x 128
{
  int t = blockIdx.x;
  int tid = threadIdx.x;  // 0..127
  int tl = t & 2047;      // t_local within batch (T=2048)
  __shared__ float w[8];
  if (tid < 8) w[tid] = wts[(size_t)t * 8 + tid];
  __syncthreads();
  float s = 0.f;
  if (tid < 64) {
    int d = tid;
    const bf16* bc = bcfs + (size_t)t * 1024;
    size_t tp = (tl == 0) ? (size_t)t : (size_t)t - 1;
    const bf16* bp = bcfs + tp * 1024;
#pragma unroll
    for (int p = 0; p < 8; p++) {
      float cur = __bfloat162float(bc[p * 64 + d]);
      float v = (tl == 0) ? cur : (0.9f * cur + 0.1f * __bfloat162float(bp[p * 64 + d]));
      s += w[p] * v;
    }
  } else {
    int d = tid - 64;
    const bf16* fsrow = bcfs + (size_t)t * 1024 + 512;
#pragma unroll
    for (int p = 0; p < 8; p++) s += w[p] * __bfloat162float(fsrow[p * 64 + d]);
  }
  comb[(size_t)t * 128 + tid] = __float2bfloat16(s);
}

extern "C" void kernel_launch(void* const* d_in, const int* in_sizes, int n_in,
                              void* d_out, int out_size, void* d_ws, size_t ws_size,
                              hipStream_t stream) {
  (void)in_sizes; (void)n_in; (void)out_size;
  const void* x   = d_in[0];   // 8192 x 4096
  const void* Wi  = d_in[1];   // 4096 x 1024
  const void* bi  = d_in[2];   // 1024
  const void* Wb  = d_in[3];   // 1024 x 512
  const void* bb  = d_in[4];   // 512
  const void* Wf  = d_in[5];   // 1024 x 512
  const void* bfv = d_in[6];   // 512
  const void* Ww  = d_in[9];   // 1024 x 8
  const void* bw  = d_in[10];  // 8
  const void* Wo  = d_in[17];  // 128 x 4096
  const void* bo  = d_in[18];  // 4096

  char* ws = (char*)d_ws;
  bf16*  h_bot = (bf16*)(ws + 0);          // 16,777,216
  bf16*  bcfs  = (bf16*)(ws + 16777216);   // 16,777,216
  bf16*  WiT   = (bf16*)(ws + 33554432);   //  8,388,608
  bf16*  WbfT  = (bf16*)(ws + 41943040);   //  2,097,152
  bf16*  WoT   = (bf16*)(ws + 44040192);   //  1,048,576
  bf16*  biC   = (bf16*)(ws + 45088768);
  bf16*  bbfC  = (bf16*)(ws + 45090816);
  bf16*  boC   = (bf16*)(ws + 45092864);
  bf16*  bwC   = (bf16*)(ws + 45101056);
  bf16*  WwC   = (bf16*)(ws + 45101184);
  float* wts   = (float*)(ws + 45117568);
  bf16*  comb  = (bf16*)(ws + 45379712);
  int*   flag  = (int*)(ws + 47476864);
  bf16*  xb    = (bf16*)(ws + 47480832);   // 67,108,864 (optional)
  const bool use_xb = ws_size >= (size_t)47480832 + 67108864;

  detect_dtype<<<1, 64, 0, stream>>>(bi, flag);

  if (use_xb)
    cvt_x<<<2048, 256, 0, stream>>>(x, xb, flag, (size_t)8192 * 4096);

  transpose_k<<<dim3(64, 16), 256, 0, stream>>>(Wi, WiT, flag, 4096, 1024);
  transpose_k<<<dim3(16, 8),  256, 0, stream>>>(Wb, WbfT, flag, 1024, 512);
  transpose_k<<<dim3(16, 8),  256, 0, stream>>>(Wf, WbfT + 512 * 1024, flag, 1024, 512);
  transpose_k<<<dim3(2, 64),  256, 0, stream>>>(Wo, WoT, flag, 128, 4096);
  cvt_misc<<<32, 256, 0, stream>>>(bi, bb, bfv, bw, bo, Ww,
                                   biC, bbfC, bwC, boC, WwC, flag);

  // GEMM1: h_bot = x @ Wi + bi.  A = xb (pure async path) when workspace
  // allows, else fp32 reg-staged fallback. 64x128 tile -> 1024 blocks.
  if (use_xb)
    gemm_bt<64, 128><<<dim3(128, 8), 256, 0, stream>>>(
        xb, WiT, biC, nullptr, h_bot, nullptr, nullptr, nullptr,
        8192, 1024, 4096, 0);
  else
    gemm_bt<64, 128><<<dim3(128, 8), 256, 0, stream>>>(
        x, WiT, biC, nullptr, h_bot, flag, nullptr, nullptr,
        8192, 1024, 4096, 0);
  // GEMM2: [bc | fs] = h_bot @ [Wb|Wf] + [bb|bf], clip cols<512
  gemm_bt<64, 128><<<dim3(128, 8), 256, 0, stream>>>(
      h_bot, WbfT, bbfC, nullptr, bcfs, nullptr, nullptr, nullptr,
      8192, 1024, 1024, 512);
  wlogits_softmax<<<8192, 256, 0, stream>>>(h_bot, WwC, bwC, wts);
  build_combined<<<8192, 128, 0, stream>>>(bcfs, wts, comb);
  // GEMM3: out = x + comb @ Wo + bo — resid = x (flagged), OUTPUT dtype follows flag (fp32)
  gemm_bt<128, 128><<<dim3(64, 32), 256, 0, stream>>>(
      comb, WoT, boC, x, d_out, nullptr, flag, flag,
      8192, 4096, 128, 0);
}

// Round 4
// 681.797 us; speedup vs baseline: 1.0822x; 1.0822x over previous
//
#include <hip/hip_runtime.h>
#include <hip/hip_bf16.h>
#include <stdint.h>

typedef __hip_bfloat16 bf16;
typedef __attribute__((ext_vector_type(8))) short short8;
typedef __attribute__((ext_vector_type(4))) float float4_t;

__device__ __forceinline__ short f2b_bits(float f) {
  union { float f; unsigned u; } v; v.f = f;
  unsigned r = (v.u + 0x7FFF + ((v.u >> 16) & 1)) >> 16;  // RNE
  return (short)r;
}
__device__ __forceinline__ bf16 f2b(float f) {
  short s = f2b_bits(f);
  bf16 h; __builtin_memcpy(&h, &s, 2);
  return h;
}
// load element idx from p (fp32 if f32 else bf16) -> bf16
__device__ __forceinline__ bf16 ld_bf16(const void* p, size_t idx, int f32) {
  if (f32) return f2b(((const float*)p)[idx]);
  return ((const bf16*)p)[idx];
}

// async global->LDS, 16B per lane. LDS dest must be wave-uniform base + lane*16.
__device__ __forceinline__ void gload_lds16(const void* g, void* l) {
  __builtin_amdgcn_global_load_lds(
      (const __attribute__((address_space(1))) void*)g,
      (__attribute__((address_space(3))) void*)l, 16, 0, 0);
}

// ---------- dtype detector: probe = bi (1024 elements) ----------
__global__ void detect_dtype(const void* probe, int* flag) {
  int lane = threadIdx.x;  // 64 threads
  const unsigned short* u = (const unsigned short*)probe;
  const float* fp = (const float*)probe;
  int cb = 0, cf = 0;
  for (int j = lane; j < 256; j += 64) {
    unsigned short he = u[2 * j];
    int e = (he >> 7) & 0xFF;
    cb += (e >= 0x60 && e <= 0x7E);
    float af = fabsf(fp[j]);
    cf += (af > 1e-9f && af < 1.0f);
  }
#pragma unroll
  for (int off = 32; off > 0; off >>= 1) {
    cb += __shfl_down(cb, off);
    cf += __shfl_down(cf, off);
  }
  if (lane == 0) *flag = (cf > cb) ? 1 : 0;  // 1 = inputs are fp32
}

// ---------- transpose: dst[n*K+k] = src[k*N+n]; K,N multiples of 64 ----------
__global__ __launch_bounds__(256) void transpose_k(const void* __restrict__ src,
                                                   bf16* __restrict__ dst,
                                                   const int* __restrict__ flagp,
                                                   int K, int N) {
  const int f32 = *flagp;
  __shared__ bf16 tile[64][65];
  int kb = blockIdx.x * 64, nb = blockIdx.y * 64;
  int tx = threadIdx.x & 63;
  int ty = threadIdx.x >> 6;  // 0..3
#pragma unroll
  for (int i = 0; i < 64; i += 4)
    tile[ty + i][tx] = ld_bf16(src, (size_t)(kb + ty + i) * N + nb + tx, f32);
  __syncthreads();
#pragma unroll
  for (int i = 0; i < 64; i += 4)
    dst[(size_t)(nb + ty + i) * K + kb + tx] = tile[tx][ty + i];
}

// ---------- Ww fused into WbfT2 rows 1024..1151 (8 real + 120 zero) ----------
__global__ __launch_bounds__(256) void cvt_wext(const void* __restrict__ Ww,
                                                const void* __restrict__ bw,
                                                bf16* __restrict__ WbfT2,
                                                bf16* __restrict__ bbf2,
                                                const int* __restrict__ flagp) {
  const int f32 = *flagp;
  int i = blockIdx.x * 256 + threadIdx.x;  // grid 512 -> 131072 threads
  if (i < 131072) {
    int r = i >> 10, k = i & 1023;
    bf16 v = (r < 8) ? ld_bf16(Ww, (size_t)k * 8 + r, f32) : f2b(0.f);
    WbfT2[(size_t)(1024 + r) * 1024 + k] = v;
  }
  if (i < 128) bbf2[1024 + i] = (i < 8) ? ld_bf16(bw, i, f32) : f2b(0.f);
}

// ---------- convert small arrays to canonical bf16 ----------
__global__ void cvt_misc(const void* bi, const void* bb, const void* bf_,
                         const void* bo,
                         bf16* biC, bf16* bbf2, bf16* boC,
                         const int* flagp) {
  const int f32 = *flagp;
  int i = blockIdx.x * 256 + threadIdx.x;
  if (i < 1024) biC[i] = ld_bf16(bi, i, f32);
  if (i < 512)  bbf2[i] = ld_bf16(bb, i, f32);
  if (i < 512)  bbf2[512 + i] = ld_bf16(bf_, i, f32);
  if (i < 4096) boC[i] = ld_bf16(bo, i, f32);
}

// ---------- split-K reduce: h = bf16(part0 + part1 + bias), N=1024 ----------
__global__ __launch_bounds__(256) void reduce2_bias(
    const float* __restrict__ part, bf16* __restrict__ h,
    const bf16* __restrict__ bias, size_t MN) {
  size_t i = ((size_t)blockIdx.x * 256 + threadIdx.x) * 8;
  size_t stride = (size_t)gridDim.x * 256 * 8;
  const float* p0 = part;
  const float* p1 = part + MN;
  for (; i < MN; i += stride) {
    float4_t a0 = *(const float4_t*)(p0 + i);
    float4_t a1 = *(const float4_t*)(p0 + i + 4);
    float4_t b0 = *(const float4_t*)(p1 + i);
    float4_t b1 = *(const float4_t*)(p1 + i + 4);
    int col = (int)(i & 1023);
    short8 out;
#pragma unroll
    for (int j = 0; j < 4; j++) {
      out[j]     = f2b_bits(a0[j] + b0[j] + __bfloat162float(bias[col + j]));
      out[j + 4] = f2b_bits(a1[j] + b1[j] + __bfloat162float(bias[col + 4 + j]));
    }
    *(short8*)(h + i) = out;
  }
}

// ---------- MFMA GEMM: C = A(MxK) * BT(NxK)^T + bias [+resid] ----------------
// BM x BN tile, BK=64, 4 waves (2x2), single-buffered (round-3 dbuf halved
// occupancy and lost: m99/m100 null + LDS cost). Optional split-K via
// gridDim.z: each z-block computes K/gz slice, writes fp32 partial to
// `part` (exact reassociation; reduce2_bias sums + bias). This gets the
// 128^2 tile's 8:1 MFMA:stage density AND >=4 blocks/CU at N=1024.
template <int BM, int BN>
__global__ __launch_bounds__(256) void gemm_bt(
    const void* __restrict__ A,      // M x K (bf16, or fp32 if *aF32)
    const bf16* __restrict__ BT,     // N x K
    const bf16* __restrict__ bias,   // N (unused if part)
    const void* __restrict__ resid,  // M x N (nullable; dtype follows rF32)
    void* __restrict__ C,            // M x N (bf16, or fp32 if *cF32)
    float* __restrict__ part,        // if non-null: fp32 partials [gz][M][N]
    const int* __restrict__ aF32, const int* __restrict__ rF32,
    const int* __restrict__ cF32,
    int M, int N, int K, int clip_cols)
{
  constexpr int FM = BM / 32;  // 16-row fragments per wave (M)
  constexpr int FN = BN / 32;  // 16-col fragments per wave (N)
  __shared__ alignas(16) bf16 As[BM * 64];
  __shared__ alignas(16) bf16 Bs[BN * 64];
  const int af32 = aF32 ? *aF32 : 0;
  const int rf32 = rF32 ? *rF32 : 0;
  const int cf32 = cF32 ? *cF32 : 0;
  const int tid  = threadIdx.x;
  const int wave = tid >> 6;
  const int lane = tid & 63;
  const int m0 = blockIdx.x * BM;
  const int n0 = blockIdx.y * BN;
  const int ks = blockIdx.z;
  const int Kper = K / gridDim.z;
  const int kbase = ks * Kper;
  const int wm = (wave >> 1) * (BM / 2);
  const int wn = (wave & 1) * (BN / 2);
  const int lm = lane & 15;
  const int lk = (lane >> 4) * 8;

  float4_t acc[FM][FN];
#pragma unroll
  for (int i = 0; i < FM; i++)
#pragma unroll
    for (int j = 0; j < FN; j++) acc[i][j] = (float4_t){0.f, 0.f, 0.f, 0.f};

  for (int kt = 0; kt < Kper; kt += 64) {
    const int k0 = kbase + kt;
    // B tile: BN rows x 64 cols, async direct-to-LDS (always bf16)
#pragma unroll
    for (int i = 0; i < BN / 32; i++) {
      int V = tid + 256 * i;
      int row = V >> 3;
      int kc  = (V & 7) * 8;
      gload_lds16(BT + (size_t)(n0 + row) * K + k0 + kc, Bs + (size_t)V * 8);
    }
    // A tile: BM rows x 64 cols
#pragma unroll
    for (int i = 0; i < BM / 32; i++) {
      int V = tid + 256 * i;
      int row = V >> 3;
      int kc  = (V & 7) * 8;
      if (af32) {
        const float* ap = (const float*)A + (size_t)(m0 + row) * K + k0 + kc;
        float4_t f0 = *(const float4_t*)ap;
        float4_t f1 = *(const float4_t*)(ap + 4);
        short8 v;
        v[0] = f2b_bits(f0[0]); v[1] = f2b_bits(f0[1]);
        v[2] = f2b_bits(f0[2]); v[3] = f2b_bits(f0[3]);
        v[4] = f2b_bits(f1[0]); v[5] = f2b_bits(f1[1]);
        v[6] = f2b_bits(f1[2]); v[7] = f2b_bits(f1[3]);
        *(short8*)(As + (size_t)V * 8) = v;
      } else {
        gload_lds16((const bf16*)A + (size_t)(m0 + row) * K + k0 + kc,
                    As + (size_t)V * 8);
      }
    }
    __syncthreads();
#pragma unroll
    for (int kk = 0; kk < 64; kk += 32) {
      short8 af[FM], bfr[FN];
#pragma unroll
      for (int mi = 0; mi < FM; mi++)
        af[mi] = *(const short8*)(As + (wm + mi * 16 + lm) * 64 + kk + lk);
#pragma unroll
      for (int ni = 0; ni < FN; ni++)
        bfr[ni] = *(const short8*)(Bs + (wn + ni * 16 + lm) * 64 + kk + lk);
#pragma unroll
      for (int mi = 0; mi < FM; mi++)
#pragma unroll
        for (int ni = 0; ni < FN; ni++)
          acc[mi][ni] = __builtin_amdgcn_mfma_f32_16x16x32_bf16(
              af[mi], bfr[ni], acc[mi][ni], 0, 0, 0);
    }
    __syncthreads();
  }

  // epilogue: C/D layout col=lane&15, row=(lane>>4)*4+r
  if (part) {
    float* dst = part + (size_t)ks * M * N;
#pragma unroll
    for (int mi = 0; mi < FM; mi++)
#pragma unroll
      for (int ni = 0; ni < FN; ni++) {
        int col = n0 + wn + ni * 16 + lm;
#pragma unroll
        for (int r = 0; r < 4; r++) {
          int row = m0 + wm + mi * 16 + (lane >> 4) * 4 + r;
          dst[(size_t)row * N + col] = acc[mi][ni][r];
        }
      }
    return;
  }
#pragma unroll
  for (int mi = 0; mi < FM; mi++) {
#pragma unroll
    for (int ni = 0; ni < FN; ni++) {
      int col = n0 + wn + ni * 16 + lm;
      float bv = __bfloat162float(bias[col]);
#pragma unroll
      for (int r = 0; r < 4; r++) {
        int row = m0 + wm + mi * 16 + (lane >> 4) * 4 + r;
        float v = acc[mi][ni][r] + bv;
        if (col < clip_cols) v = fminf(fmaxf(v, -10.f), 10.f);
        size_t idx = (size_t)row * N + col;
        if (resid) {
          v += rf32 ? ((const float*)resid)[idx]
                    : __bfloat162float(((const bf16*)resid)[idx]);
        }
        if (cf32) ((float*)C)[idx] = v;
        else      ((bf16*)C)[idx] = __float2bfloat16(v);
      }
    }
  }
}

// ---------- per-token: softmax over fused logit cols + temporal mix + agg ----
__global__ __launch_bounds__(128) void build_combined(
    const bf16* __restrict__ bcfs,  // 8192 x 1152: 0..511 bc, 512..1023 fs, 1024..1031 logits
    bf16* __restrict__ comb)        // 8192 x 128
{
  int t = blockIdx.x;
  int tid = threadIdx.x;  // 0..127
  int tl = t & 2047;      // t_local within batch (T=2048)
  __shared__ float lg[8];
  __shared__ float w[8];
  if (tid < 8) lg[tid] = __bfloat162float(bcfs[(size_t)t * 1152 + 1024 + tid]);
  __syncthreads();
  if (tid < 8) {
    float mx = lg[0];
#pragma unroll
    for (int i = 1; i < 8; i++) mx = fmaxf(mx, lg[i]);
    float den = 0.f;
#pragma unroll
    for (int i = 0; i < 8; i++) den += expf(lg[i] - mx);
    w[tid] = expf(lg[tid] - mx) / den;
  }
  __syncthreads();
  float s = 0.f;
  if (tid < 64) {
    int d = tid;
    const bf16* bc = bcfs + (size_t)t * 1152;
    size_t tp = (tl == 0) ? (size_t)t : (size_t)t - 1;
    const bf16* bp = bcfs + tp * 1152;
#pragma unroll
    for (int p = 0; p < 8; p++) {
      float cur = __bfloat162float(bc[p * 64 + d]);
      float v = (tl == 0) ? cur : (0.9f * cur + 0.1f * __bfloat162float(bp[p * 64 + d]));
      s += w[p] * v;
    }
  } else {
    int d = tid - 64;
    const bf16* fsrow = bcfs + (size_t)t * 1152 + 512;
#pragma unroll
    for (int p = 0; p < 8; p++) s += w[p] * __bfloat162float(fsrow[p * 64 + d]);
  }
  comb[(size_t)t * 128 + tid] = __float2bfloat16(s);
}

extern "C" void kernel_launch(void* const* d_in, const int* in_sizes, int n_in,
                              void* d_out, int out_size, void* d_ws, size_t ws_size,
                              hipStream_t stream) {
  (void)in_sizes; (void)n_in; (void)out_size;
  const void* x   = d_in[0];   // 8192 x 4096
  const void* Wi  = d_in[1];   // 4096 x 1024
  const void* bi  = d_in[2];   // 1024
  const void* Wb  = d_in[3];   // 1024 x 512
  const void* bb  = d_in[4];   // 512
  const void* Wf  = d_in[5];   // 1024 x 512
  const void* bfv = d_in[6];   // 512
  const void* Ww  = d_in[9];   // 1024 x 8
  const void* bw  = d_in[10];  // 8
  const void* Wo  = d_in[17];  // 128 x 4096
  const void* bo  = d_in[18];  // 4096

  char* ws = (char*)d_ws;
  bf16*  h_bot = (bf16*)(ws + 0);          // 16,777,216 (comb aliases after GEMM2)
  bf16*  comb  = (bf16*)(ws + 0);          // 2,097,152 alias: h_bot dead after GEMM2
  bf16*  bcfs  = (bf16*)(ws + 16777216);   // 8192x1152x2 = 18,874,368
  bf16*  WiT   = (bf16*)(ws + 35651584);   //  8,388,608
  bf16*  WbfT2 = (bf16*)(ws + 44040192);   // 1152x1024x2 = 2,359,296
  bf16*  WoT   = (bf16*)(ws + 46399488);   //  1,048,576
  bf16*  biC   = (bf16*)(ws + 47448064);   //      2,048
  bf16*  bbf2C = (bf16*)(ws + 47450112);   //      2,304
  bf16*  boC   = (bf16*)(ws + 47452416);   //      8,192
  int*   flag  = (int*)(ws + 47460608);    //          4
  float* hpart = (float*)(ws + 47464448);  // 67,108,864 (optional, split-K)
  const bool use_splitk = ws_size >= (size_t)47464448 + 67108864;

  detect_dtype<<<1, 64, 0, stream>>>(bi, flag);

  transpose_k<<<dim3(64, 16), 256, 0, stream>>>(Wi, WiT, flag, 4096, 1024);
  transpose_k<<<dim3(16, 8),  256, 0, stream>>>(Wb, WbfT2, flag, 1024, 512);
  transpose_k<<<dim3(16, 8),  256, 0, stream>>>(Wf, WbfT2 + 512 * 1024, flag, 1024, 512);
  transpose_k<<<dim3(2, 64),  256, 0, stream>>>(Wo, WoT, flag, 128, 4096);
  cvt_wext<<<512, 256, 0, stream>>>(Ww, bw, WbfT2, bbf2C, flag);
  cvt_misc<<<16, 256, 0, stream>>>(bi, bb, bfv, bo, biC, bbf2C, boC, flag);

  // GEMM1: h_bot = x @ Wi + bi.
  // Split-K=2 (fp32 partials, exact): 128x128 tile at grid 64x8x2 = 1024
  // blocks = 4/CU with full 8:1 MFMA:stage density (m97 configuration).
  if (use_splitk) {
    gemm_bt<128, 128><<<dim3(64, 8, 2), 256, 0, stream>>>(
        x, WiT, nullptr, nullptr, nullptr, hpart, flag, nullptr, nullptr,
        8192, 1024, 4096, 0);
    reduce2_bias<<<2048, 256, 0, stream>>>(hpart, h_bot, biC,
                                           (size_t)8192 * 1024);
  } else {
    gemm_bt<64, 128><<<dim3(128, 8), 256, 0, stream>>>(
        x, WiT, biC, nullptr, h_bot, nullptr, flag, nullptr, nullptr,
        8192, 1024, 4096, 0);
  }
  // GEMM2: [bc | fs | logits | pad] = h_bot @ [Wb|Wf|Ww|0] + [bb|bf|bw|0]
  gemm_bt<64, 128><<<dim3(128, 9), 256, 0, stream>>>(
      h_bot, WbfT2, bbf2C, nullptr, bcfs, nullptr, nullptr, nullptr, nullptr,
      8192, 1152, 1024, 512);
  build_combined<<<8192, 128, 0, stream>>>(bcfs, comb);
  // GEMM3: out = x + comb @ Wo + bo — resid = x (flagged), OUTPUT dtype follows flag
  gemm_bt<128, 128><<<dim3(64, 32), 256, 0, stream>>>(
      comb, WoT, boC, x, d_out, nullptr, nullptr, flag, flag,
      8192, 4096, 128, 0);
}

// Round 5
// 568.394 us; speedup vs baseline: 1.2981x; 1.1995x over previous
//
#include <hip/hip_runtime.h>
#include <hip/hip_bf16.h>
#include <stdint.h>

typedef __hip_bfloat16 bf16;
typedef __attribute__((ext_vector_type(8))) short short8;
typedef __attribute__((ext_vector_type(4))) float float4_t;

__device__ __forceinline__ short f2b_bits(float f) {
  union { float f; unsigned u; } v; v.f = f;
  unsigned r = (v.u + 0x7FFF + ((v.u >> 16) & 1)) >> 16;  // RNE
  return (short)r;
}
__device__ __forceinline__ bf16 f2b(float f) {
  short s = f2b_bits(f);
  bf16 h; __builtin_memcpy(&h, &s, 2);
  return h;
}
// load element idx from p (fp32 if f32 else bf16) -> bf16
__device__ __forceinline__ bf16 ld_bf16(const void* p, size_t idx, int f32) {
  if (f32) return f2b(((const float*)p)[idx]);
  return ((const bf16*)p)[idx];
}

// async global->LDS, 16B per lane. LDS dest must be wave-uniform base + lane*16.
__device__ __forceinline__ void gload_lds16(const void* g, void* l) {
  __builtin_amdgcn_global_load_lds(
      (const __attribute__((address_space(1))) void*)g,
      (__attribute__((address_space(3))) void*)l, 16, 0, 0);
}

// ---------- dtype detector: probe = bi (1024 elements) ----------
__global__ void detect_dtype(const void* probe, int* flag) {
  int lane = threadIdx.x;  // 64 threads
  const unsigned short* u = (const unsigned short*)probe;
  const float* fp = (const float*)probe;
  int cb = 0, cf = 0;
  for (int j = lane; j < 256; j += 64) {
    unsigned short he = u[2 * j];
    int e = (he >> 7) & 0xFF;
    cb += (e >= 0x60 && e <= 0x7E);
    float af = fabsf(fp[j]);
    cf += (af > 1e-9f && af < 1.0f);
  }
#pragma unroll
  for (int off = 32; off > 0; off >>= 1) {
    cb += __shfl_down(cb, off);
    cf += __shfl_down(cf, off);
  }
  if (lane == 0) *flag = (cf > cb) ? 1 : 0;  // 1 = inputs are fp32
}

// ---------- all 4 weight transposes in ONE launch (range-decoded) ----------
// dst[n*K+k] = src[k*N+n]; K,N multiples of 64.
__global__ __launch_bounds__(256) void transpose_all(
    const void* __restrict__ Wi, const void* __restrict__ Wb,
    const void* __restrict__ Wf, const void* __restrict__ Wo,
    bf16* __restrict__ WiT, bf16* __restrict__ WbfT2, bf16* __restrict__ WoT,
    const int* __restrict__ flagp)
{
  const int f32 = *flagp;
  int b = blockIdx.x;
  const void* src; bf16* dst; int K, N, tb;
  if (b < 1024)      { src = Wi; dst = WiT;              K = 4096; N = 1024; tb = b; }
  else if (b < 1152) { src = Wb; dst = WbfT2;            K = 1024; N = 512;  tb = b - 1024; }
  else if (b < 1280) { src = Wf; dst = WbfT2 + 512*1024; K = 1024; N = 512;  tb = b - 1152; }
  else               { src = Wo; dst = WoT;              K = 128;  N = 4096; tb = b - 1280; }
  int nbk = K >> 6;
  int kb = (tb % nbk) * 64, nb = (tb / nbk) * 64;
  __shared__ bf16 tile[64][65];
  int tx = threadIdx.x & 63;
  int ty = threadIdx.x >> 6;  // 0..3
#pragma unroll
  for (int i = 0; i < 64; i += 4)
    tile[ty + i][tx] = ld_bf16(src, (size_t)(kb + ty + i) * N + nb + tx, f32);
  __syncthreads();
#pragma unroll
  for (int i = 0; i < 64; i += 4)
    dst[(size_t)(nb + ty + i) * K + kb + tx] = tile[tx][ty + i];
}

// ---------- small conversions + Ww fused into WbfT2 rows 1024..1151 ----------
__global__ __launch_bounds__(256) void cvt_small(
    const void* __restrict__ Ww, const void* __restrict__ bw,
    const void* __restrict__ bi, const void* __restrict__ bb,
    const void* __restrict__ bf_, const void* __restrict__ bo,
    bf16* __restrict__ WbfT2, bf16* __restrict__ bbf2,
    bf16* __restrict__ biC, bf16* __restrict__ boC,
    const int* __restrict__ flagp)
{
  const int f32 = *flagp;
  int i = blockIdx.x * 256 + threadIdx.x;  // grid 512 -> 131072 threads
  if (i < 131072) {
    int r = i >> 10, k = i & 1023;
    bf16 v = (r < 8) ? ld_bf16(Ww, (size_t)k * 8 + r, f32) : f2b(0.f);
    WbfT2[(size_t)(1024 + r) * 1024 + k] = v;
  }
  if (i < 128) bbf2[1024 + i] = (i < 8) ? ld_bf16(bw, i, f32) : f2b(0.f);
  if (i < 1024) biC[i] = ld_bf16(bi, i, f32);
  if (i < 512)  bbf2[i] = ld_bf16(bb, i, f32);
  if (i < 512)  bbf2[512 + i] = ld_bf16(bf_, i, f32);
  if (i < 4096) boC[i] = ld_bf16(bo, i, f32);
}

// ---------- MFMA GEMM: C = A(MxK) * BT(NxK)^T + bias [+resid] ----------------
// BM x BN tile, BK=64, 4 waves (2x2), single-buffered 2-barrier loop.
// 64x128 is the measured-best config at these shapes: VGPR 44 + 32 AGPR ->
// 6 blocks/CU capacity, grids >=1024 fully resident (R2: 42.5% occ,
// MfmaUtil 16.5%). 128^2 acc (64 AGPR) caps at 3 blocks/CU -> dispatch
// tail (R4: 25.5% occ, lost). dbuf halves residency (R3, lost).
template <int BM, int BN>
__global__ __launch_bounds__(256) void gemm_bt(
    const void* __restrict__ A,      // M x K (bf16, or fp32 if *aF32)
    const bf16* __restrict__ BT,     // N x K
    const bf16* __restrict__ bias,   // N
    const void* __restrict__ resid,  // M x N (nullable; dtype follows rF32)
    void* __restrict__ C,            // M x N (bf16, or fp32 if *cF32)
    const int* __restrict__ aF32, const int* __restrict__ rF32,
    const int* __restrict__ cF32,
    int M, int N, int K, int clip_cols)
{
  constexpr int FM = BM / 32;  // 16-row fragments per wave (M)
  constexpr int FN = BN / 32;  // 16-col fragments per wave (N)
  __shared__ alignas(16) bf16 As[BM * 64];
  __shared__ alignas(16) bf16 Bs[BN * 64];
  const int af32 = aF32 ? *aF32 : 0;
  const int rf32 = rF32 ? *rF32 : 0;
  const int cf32 = cF32 ? *cF32 : 0;
  const int tid  = threadIdx.x;
  const int wave = tid >> 6;
  const int lane = tid & 63;
  const int m0 = blockIdx.x * BM;
  const int n0 = blockIdx.y * BN;
  const int wm = (wave >> 1) * (BM / 2);
  const int wn = (wave & 1) * (BN / 2);
  const int lm = lane & 15;
  const int lk = (lane >> 4) * 8;

  float4_t acc[FM][FN];
#pragma unroll
  for (int i = 0; i < FM; i++)
#pragma unroll
    for (int j = 0; j < FN; j++) acc[i][j] = (float4_t){0.f, 0.f, 0.f, 0.f};

  for (int k0 = 0; k0 < K; k0 += 64) {
    // B tile: BN rows x 64 cols, async direct-to-LDS (always bf16)
#pragma unroll
    for (int i = 0; i < BN / 32; i++) {
      int V = tid + 256 * i;
      int row = V >> 3;
      int kc  = (V & 7) * 8;
      gload_lds16(BT + (size_t)(n0 + row) * K + k0 + kc, Bs + (size_t)V * 8);
    }
    // A tile: BM rows x 64 cols
#pragma unroll
    for (int i = 0; i < BM / 32; i++) {
      int V = tid + 256 * i;
      int row = V >> 3;
      int kc  = (V & 7) * 8;
      if (af32) {
        const float* ap = (const float*)A + (size_t)(m0 + row) * K + k0 + kc;
        float4_t f0 = *(const float4_t*)ap;
        float4_t f1 = *(const float4_t*)(ap + 4);
        short8 v;
        v[0] = f2b_bits(f0[0]); v[1] = f2b_bits(f0[1]);
        v[2] = f2b_bits(f0[2]); v[3] = f2b_bits(f0[3]);
        v[4] = f2b_bits(f1[0]); v[5] = f2b_bits(f1[1]);
        v[6] = f2b_bits(f1[2]); v[7] = f2b_bits(f1[3]);
        *(short8*)(As + (size_t)V * 8) = v;
      } else {
        gload_lds16((const bf16*)A + (size_t)(m0 + row) * K + k0 + kc,
                    As + (size_t)V * 8);
      }
    }
    __syncthreads();
#pragma unroll
    for (int kk = 0; kk < 64; kk += 32) {
      short8 af[FM], bfr[FN];
#pragma unroll
      for (int mi = 0; mi < FM; mi++)
        af[mi] = *(const short8*)(As + (wm + mi * 16 + lm) * 64 + kk + lk);
#pragma unroll
      for (int ni = 0; ni < FN; ni++)
        bfr[ni] = *(const short8*)(Bs + (wn + ni * 16 + lm) * 64 + kk + lk);
#pragma unroll
      for (int mi = 0; mi < FM; mi++)
#pragma unroll
        for (int ni = 0; ni < FN; ni++)
          acc[mi][ni] = __builtin_amdgcn_mfma_f32_16x16x32_bf16(
              af[mi], bfr[ni], acc[mi][ni], 0, 0, 0);
    }
    __syncthreads();
  }

  // epilogue: C/D layout col=lane&15, row=(lane>>4)*4+r
#pragma unroll
  for (int mi = 0; mi < FM; mi++) {
#pragma unroll
    for (int ni = 0; ni < FN; ni++) {
      int col = n0 + wn + ni * 16 + lm;
      float bv = __bfloat162float(bias[col]);
#pragma unroll
      for (int r = 0; r < 4; r++) {
        int row = m0 + wm + mi * 16 + (lane >> 4) * 4 + r;
        float v = acc[mi][ni][r] + bv;
        if (col < clip_cols) v = fminf(fmaxf(v, -10.f), 10.f);
        size_t idx = (size_t)row * N + col;
        if (resid) {
          v += rf32 ? ((const float*)resid)[idx]
                    : __bfloat162float(((const bf16*)resid)[idx]);
        }
        if (cf32) ((float*)C)[idx] = v;
        else      ((bf16*)C)[idx] = __float2bfloat16(v);
      }
    }
  }
}

// ---------- per-token: softmax over fused logit cols + temporal mix + agg ----
__global__ __launch_bounds__(128) void build_combined(
    const bf16* __restrict__ bcfs,  // 8192 x 1152: 0..511 bc, 512..1023 fs, 1024..1031 logits
    bf16* __restrict__ comb)        // 8192 x 128
{
  int t = blockIdx.x;
  int tid = threadIdx.x;  // 0..127
  int tl = t & 2047;      // t_local within batch (T=2048)
  __shared__ float lg[8];
  __shared__ float w[8];
  if (tid < 8) lg[tid] = __bfloat162float(bcfs[(size_t)t * 1152 + 1024 + tid]);
  __syncthreads();
  if (tid < 8) {
    float mx = lg[0];
#pragma unroll
    for (int i = 1; i < 8; i++) mx = fmaxf(mx, lg[i]);
    float den = 0.f;
#pragma unroll
    for (int i = 0; i < 8; i++) den += expf(lg[i] - mx);
    w[tid] = expf(lg[tid] - mx) / den;
  }
  __syncthreads();
  float s = 0.f;
  if (tid < 64) {
    int d = tid;
    const bf16* bc = bcfs + (size_t)t * 1152;
    size_t tp = (tl == 0) ? (size_t)t : (size_t)t - 1;
    const bf16* bp = bcfs + tp * 1152;
#pragma unroll
    for (int p = 0; p < 8; p++) {
      float cur = __bfloat162float(bc[p * 64 + d]);
      float v = (tl == 0) ? cur : (0.9f * cur + 0.1f * __bfloat162float(bp[p * 64 + d]));
      s += w[p] * v;
    }
  } else {
    int d = tid - 64;
    const bf16* fsrow = bcfs + (size_t)t * 1152 + 512;
#pragma unroll
    for (int p = 0; p < 8; p++) s += w[p] * __bfloat162float(fsrow[p * 64 + d]);
  }
  comb[(size_t)t * 128 + tid] = __float2bfloat16(s);
}

extern "C" void kernel_launch(void* const* d_in, const int* in_sizes, int n_in,
                              void* d_out, int out_size, void* d_ws, size_t ws_size,
                              hipStream_t stream) {
  (void)in_sizes; (void)n_in; (void)out_size; (void)ws_size;
  const void* x   = d_in[0];   // 8192 x 4096
  const void* Wi  = d_in[1];   // 4096 x 1024
  const void* bi  = d_in[2];   // 1024
  const void* Wb  = d_in[3];   // 1024 x 512
  const void* bb  = d_in[4];   // 512
  const void* Wf  = d_in[5];   // 1024 x 512
  const void* bfv = d_in[6];   // 512
  const void* Ww  = d_in[9];   // 1024 x 8
  const void* bw  = d_in[10];  // 8
  const void* Wo  = d_in[17];  // 128 x 4096
  const void* bo  = d_in[18];  // 4096

  char* ws = (char*)d_ws;
  bf16*  h_bot = (bf16*)(ws + 0);          // 16,777,216 (comb aliases after GEMM2)
  bf16*  comb  = (bf16*)(ws + 0);          // 2,097,152 alias: h_bot dead after GEMM2
  bf16*  bcfs  = (bf16*)(ws + 16777216);   // 8192x1152x2 = 18,874,368
  bf16*  WiT   = (bf16*)(ws + 35651584);   //  8,388,608
  bf16*  WbfT2 = (bf16*)(ws + 44040192);   // 1152x1024x2 = 2,359,296
  bf16*  WoT   = (bf16*)(ws + 46399488);   //  1,048,576
  bf16*  biC   = (bf16*)(ws + 47448064);   //      2,048
  bf16*  bbf2C = (bf16*)(ws + 47450112);   //      2,304
  bf16*  boC   = (bf16*)(ws + 47452416);   //      8,192
  int*   flag  = (int*)(ws + 47460608);    //          4

  detect_dtype<<<1, 64, 0, stream>>>(bi, flag);

  transpose_all<<<1408, 256, 0, stream>>>(Wi, Wb, Wf, Wo, WiT, WbfT2, WoT, flag);
  cvt_small<<<512, 256, 0, stream>>>(Ww, bw, bi, bb, bfv, bo,
                                     WbfT2, bbf2C, biC, boC, flag);

  // GEMM1: h_bot = x @ Wi + bi  (A = x fp32-flagged; 64x128, grid 1024 = 4/CU)
  gemm_bt<64, 128><<<dim3(128, 8), 256, 0, stream>>>(
      x, WiT, biC, nullptr, h_bot, flag, nullptr, nullptr,
      8192, 1024, 4096, 0);
  // GEMM2: [bc | fs | logits | pad] = h_bot @ [Wb|Wf|Ww|0] + [bb|bf|bw|0]
  gemm_bt<64, 128><<<dim3(128, 9), 256, 0, stream>>>(
      h_bot, WbfT2, bbf2C, nullptr, bcfs, nullptr, nullptr, nullptr,
      8192, 1152, 1024, 512);
  build_combined<<<8192, 128, 0, stream>>>(bcfs, comb);
  // GEMM3: out = x + comb @ Wo + bo — resid = x (flagged), OUTPUT dtype follows
  // flag. 64x128 (grid 4096): K=128 = 2 K-steps -> prologue-latency-bound;
  // small acc (32 AGPR) + big grid maximizes overlap.
  gemm_bt<64, 128><<<dim3(128, 32), 256, 0, stream>>>(
      comb, WoT, boC, x, d_out, nullptr, flag, flag,
      8192, 4096, 128, 0);
}